// Round 8
// baseline (45.835 us; speedup 1.0000x reference)
//
#include <hip/hip_runtime.h>
#include <math.h>

// Problem constants
#define NB 256   // batches
#define NN 32    // agents
#define DD 128   // state dim
#define NA 16    // action dim
#define HH 256   // hidden

using f32x4v  = __attribute__((ext_vector_type(4))) float;
using bf16x8  = __attribute__((ext_vector_type(8))) short;

static __device__ __forceinline__ float4 ld4(const float* p){ return *reinterpret_cast<const float4*>(p); }
static __device__ __forceinline__ void st4f(float* p, float4 v){ *reinterpret_cast<float4*>(p) = v; }
static __device__ __forceinline__ float elem(float4 v, int kk){
    return (kk==0)?v.x:(kk==1)?v.y:(kk==2)?v.z:v.w;
}

static __device__ __forceinline__ unsigned f2bf(float x){
    unsigned u = __float_as_uint(x);
    u += 0x7fffu + ((u >> 16) & 1u);   // round-to-nearest-even
    return u >> 16;
}
static __device__ __forceinline__ unsigned pack2(float a, float b){
    return f2bf(a) | (f2bf(b) << 16);
}
static __device__ __forceinline__ float bf2f(unsigned short s){
    return __uint_as_float(((unsigned)s) << 16);
}

static __device__ __forceinline__ f32x4v mfma16(bf16x8 a, bf16x8 b, f32x4v c){
    return __builtin_amdgcn_mfma_f32_16x16x32_bf16(a, b, c, 0, 0, 0);
}

// write one B-fragment (16 bf16 bytes per lane) to the swizzled weight buffer
static __device__ __forceinline__ void store_frag(unsigned short* __restrict__ dst,
                                                  int frag, int l, const float v[8]){
    uint4 p;
    p.x = pack2(v[0], v[1]); p.y = pack2(v[2], v[3]);
    p.z = pack2(v[4], v[5]); p.w = pack2(v[6], v[7]);
    *reinterpret_cast<uint4*>(dst + (size_t)(frag*64 + l)*8) = p;
}

// =============================================================================
// k_pre0 (52 blocks x 512):
//   blocks 0..31 : T2 = Wav @ W1, strip of 4 rows each. W1 staged via LDS in
//                  16-row chunks (coalesced). 256 FMA/thread, no long chains.
//   blocks 32..51: fragment-swizzled bf16 copies of the 5 attention weights
//                  (160 frags total, 8 per block).
// =============================================================================
__global__ __launch_bounds__(512)
void k_pre0(const float* __restrict__ Wav, const float* __restrict__ W1,
            const float* __restrict__ Wqp, const float* __restrict__ Wkp,
            const float* __restrict__ Wvp, const float* __restrict__ Wq,
            const float* __restrict__ Wk,
            float* __restrict__ T2g,
            unsigned short* __restrict__ Wqps, unsigned short* __restrict__ Wkps,
            unsigned short* __restrict__ Wvps, unsigned short* __restrict__ Wqs,
            unsigned short* __restrict__ Wks)
{
    const int t = threadIdx.x;
    const int bid = blockIdx.x;

    if (bid < 32) {
        __shared__ float WavR[4*128];   // 4 rows of Wav
        __shared__ float W1c[16*256];   // W1 k-chunk
        if (t < 128) st4f(WavR + t*4, ld4(Wav + (size_t)bid*4*128 + t*4));

        const int c  = t & 255;
        const int rp = (t >> 8) * 2;    // rows rp, rp+1 of the strip
        float acc0 = 0.f, acc1 = 0.f;

        for (int ch = 0; ch < 8; ch++) {
            __syncthreads();  // W1c reuse (also covers initial WavR staging)
            #pragma unroll
            for (int u = 0; u < 2; u++) {
                int idx = t + 512*u;            // float4 index 0..1023
                int row = idx >> 6, c4 = (idx & 63) * 4;
                st4f(W1c + row*256 + c4, ld4(W1 + (size_t)(ch*16 + row)*256 + c4));
            }
            __syncthreads();
            #pragma unroll
            for (int kk = 0; kk < 16; kk++) {
                float w  = W1c[kk*256 + c];
                acc0 = fmaf(WavR[rp*128     + ch*16 + kk], w, acc0);
                acc1 = fmaf(WavR[(rp+1)*128 + ch*16 + kk], w, acc1);
            }
        }
        T2g[(size_t)(bid*4 + rp)*256 + c]     = acc0;
        T2g[(size_t)(bid*4 + rp + 1)*256 + c] = acc1;
    } else {
        // 8 frags per block; 160 frags = 5 weights x 32
        const int bb = bid - 32;
        const int fg = bb*8 + (t >> 6);
        const int l  = t & 63;
        const int sel = fg >> 5, frag = fg & 31;
        const int kt = frag >> 3, nt = frag & 7;
        const float* W = (sel==0) ? Wqp : (sel==1) ? Wkp : (sel==2) ? Wvp :
                         (sel==3) ? Wq : Wk;
        unsigned short* dst = (sel==0) ? Wqps : (sel==1) ? Wkps : (sel==2) ? Wvps :
                              (sel==3) ? Wqs : Wks;
        float v[8];
        #pragma unroll
        for (int i = 0; i < 8; i++)
            v[i] = W[(kt*32 + (l>>4)*8 + i)*128 + nt*16 + (l&15)];
        store_frag(dst, frag, l, v);
    }
}

// =============================================================================
// k_pre1 (16 blocks x 512): WAB = We @ T2 per 16-col tile ct.
//   We staged in 48-row LDS chunks (coalesced); T2 16-col slice transposed in
//   LDS (k-contiguous for float4). Emits bf16 frags (kt 0..4, nt=ct) with
//   rows 144..159 zero-padded, + fp32 rows 128..143 -> WABf.
// =============================================================================
__global__ __launch_bounds__(512)
void k_pre1(const float* __restrict__ We, const float* __restrict__ T2g,
            float* __restrict__ WABf, unsigned short* __restrict__ WABs)
{
    __shared__ float T2c[16*132];   // transposed: T2c[c][k], pitch 132
    __shared__ float WeC[48*128];   // 48-row We chunk
    __shared__ float WABt[160*16];  // output col-tile fp32

    const int t = threadIdx.x;
    const int ct = blockIdx.x;

    // stage T2 slice transposed: thread loads one float4 (row, 4 cols)
    {
        int row = t >> 2, c4 = (t & 3) * 4;
        float4 v = ld4(T2g + (size_t)row*256 + ct*16 + c4);
        T2c[(c4+0)*132 + row] = v.x;
        T2c[(c4+1)*132 + row] = v.y;
        T2c[(c4+2)*132 + row] = v.z;
        T2c[(c4+3)*132 + row] = v.w;
    }
    // zero pad rows 144..159
    if (t < 256) WABt[(144 + (t>>4))*16 + (t&15)] = 0.f;

    const int rg = t >> 4;   // 0..31
    const int c  = t & 15;

    for (int c3 = 0; c3 < 3; c3++) {
        const int rows48 = c3 * 48;
        __syncthreads();   // WeC reuse (first iter: also T2c staging)
        #pragma unroll
        for (int u = 0; u < 3; u++) {
            int idx = t + 512*u;            // float4 index 0..1535
            int row = idx >> 5, c4 = (idx & 31) * 4;
            st4f(WeC + row*128 + c4, ld4(We + (size_t)(rows48 + row)*128 + c4));
        }
        __syncthreads();

        float accA = 0.f, accB = 0.f;
        #pragma unroll 4
        for (int k0 = 0; k0 < 128; k0 += 4) {
            float4 wa = ld4(WeC + rg*128 + k0);
            float4 wb = ld4(WeC + (rg+32)*128 + k0);   // rg<16 only used
            float4 tv = ld4(T2c + c*132 + k0);
            #pragma unroll
            for (int kk = 0; kk < 4; kk++) {
                float tvk = elem(tv, kk);
                accA = fmaf(elem(wa,kk), tvk, accA);
                accB = fmaf(elem(wb,kk), tvk, accB);
            }
        }
        WABt[(rows48 + rg)*16 + c] = accA;
        if (rg < 16) {
            WABt[(rows48 + rg + 32)*16 + c] = accB;
            if (c3 == 2)   // global rows 128..143
                WABf[(size_t)(128 + rg)*256 + ct*16 + c] = accB;
        }
    }
    __syncthreads();

    // swizzle-emit 5 frags (kt=0..4, nt=ct)
    if (t < 320) {
        int kt = t >> 6, l = t & 63;
        float v[8];
        #pragma unroll
        for (int i = 0; i < 8; i++)
            v[i] = WABt[(kt*32 + (l>>4)*8 + i)*16 + (l&15)];
        store_frag(WABs, kt*16 + ct, l, v);
    }
}

// scores+softmax, 512 threads: thread (i=t>>4, j=t&15) covers (i,j) and (i,j+16).
static __device__ __forceinline__ void scores_softmax512(const float* __restrict__ Qm,
                                                         const float* __restrict__ Km,
                                                         float scale,
                                                         float* __restrict__ w_lds,
                                                         float* __restrict__ w_out,
                                                         int i, int j)
{
    float s0 = 0.f, s1 = 0.f;
    #pragma unroll 4
    for (int k=0;k<128;k+=4){
        float4 qv = ld4(Qm + i*132 + k);
        float4 k0 = ld4(Km + j*132 + k);
        float4 k1 = ld4(Km + (j+16)*132 + k);
        s0 += qv.x*k0.x + qv.y*k0.y + qv.z*k0.z + qv.w*k0.w;
        s1 += qv.x*k1.x + qv.y*k1.y + qv.z*k1.z + qv.w*k1.w;
    }
    s0 *= scale; s1 *= scale;
    float m = fmaxf(s0, s1);
    #pragma unroll
    for (int d=1; d<16; d<<=1) m = fmaxf(m, __shfl_xor(m, d));
    float e0 = expf(s0 - m), e1 = expf(s1 - m);
    float sum = e0 + e1;
    #pragma unroll
    for (int d=1; d<16; d<<=1) sum += __shfl_xor(sum, d);
    float inv = 1.f / sum;
    e0 *= inv; e1 *= inv;
    w_lds[i*36 + j]      = e0;
    w_lds[i*36 + j + 16] = e1;
    w_out[i*32 + j]      = e0;
    w_out[i*32 + j + 16] = e1;
}

// =============================================================================
// k_main: one block per batch, 512 threads (8 waves). Identical to R7.
// =============================================================================
__global__ __launch_bounds__(512)
void k_main(const float* __restrict__ states, const float* __restrict__ pol,
            const float* __restrict__ act,
            const unsigned short* __restrict__ Wqps, const unsigned short* __restrict__ Wkps,
            const unsigned short* __restrict__ Wvps, const unsigned short* __restrict__ Wqs,
            const unsigned short* __restrict__ Wks,  const unsigned short* __restrict__ WABs,
            const float* __restrict__ WABf, const float* __restrict__ W2,
            float* __restrict__ out_v, float* __restrict__ out_w1,
            float* __restrict__ out_w2)
{
    const int b = blockIdx.x;
    const int t = threadIdx.x;
    const float scale = 0.08838834764831845f;  // 1/sqrt(128)

    __shared__ float SH[16000];   // 62.5 KB
    float* B1   = SH;                                   // 32x132
    float* B2   = SH + 4224;                            // 32x132
    float* Wb2f = SH + 8448;                            // 32x36
    float* Wb1f = SH + 9600;                            // 32x36
    float* APd  = SH + 10752;                           // 32x16 (pol-act)
    unsigned short* Xoa  = (unsigned short*)(SH + 11264); // [32][168] bf16 (st|act|0)
    unsigned short* Ubf  = (unsigned short*)B1;           // [32][136] bf16
    unsigned short* Wvbf = (unsigned short*)B2;           // [32][136] bf16
    float*    A1 = SH;                                   // [32][260] fp32 (over B1+B2)
    unsigned* P2 = (unsigned*)(SH + 11904);              // [32][128] packed bf16 (over dead Xoa)
    unsigned* Q2 = (unsigned*)SH;                        // [32][132] packed bf16 (over dead A1)
    float* SPQ = Wb1f;   // SP[32][2] at 0, SQ[32][2] at +64 (Wb1f dead after P3)

    const float* stg  = states + (size_t)b*(NN*DD);
    const float* actg = act + (size_t)b*(NN*NA);
    const float* polg = pol + (size_t)b*(NN*NA);

    // ---- stage Xoa = bf16([st | act | 0]) (k 0..159), APd = pol-act ----
    {
        int r = t >> 4, kb = t & 15;
        #pragma unroll
        for (int uu = 0; uu < 10; uu++){
            int k = kb + 16*uu;
            float v = (k < 128) ? stg[r*128 + k]
                    : (k < 144) ? actg[r*16 + (k-128)] : 0.f;
            Xoa[r*168 + k] = (unsigned short)f2bf(v);
        }
        if (t < 128) {
            int rr = t>>2, cc = (t&3)*4;
            float4 p = ld4(polg + rr*16 + cc), a = ld4(actg + rr*16 + cc);
            st4f(APd + rr*16 + cc, make_float4(p.x-a.x, p.y-a.y, p.z-a.z, p.w-a.w));
        }
    }
    __syncthreads();

    // MFMA wave geometry
    const int l    = t & 63;
    const int wv   = t >> 6;             // wave 0..7
    const int mt   = wv & 1;             // M-tile
    const int ntb  = (wv >> 1) * 2;      // N-tile base (128-col GEMMs)
    const int nb7  = (wv >> 1) * 4;      // N-tile base (256-col GEMM)
    const int arow = mt*16 + (l & 15);
    const int drow = mt*16 + ((l >> 4) << 2);
    const int dcol = l & 15;

    // VALU phase geometry
    const int c  = t & 127;
    const int g  = t >> 7;
    const int cp = (t & 127)*2;
    const int si = t >> 4;
    const int sj = t & 15;
    const int wp = wv & 1;

    // ---- Q-hoist (VALU): Q = (pol-act)@WB (K=16) -> regs + SQ butterfly ----
    float qr0[8], qr1[8], sq[8];
    {
        #pragma unroll
        for (int u=0;u<8;u++){ qr0[u]=0.f; qr1[u]=0.f; }
        const float* wB = WABf + 128*256;
        #pragma unroll
        for (int k0=0;k0<16;k0+=4){
            float4 xv[8];
            #pragma unroll
            for (int u=0;u<8;u++) xv[u] = ld4(APd + (g*8+u)*16 + k0);
            #pragma unroll
            for (int kk=0;kk<4;kk++){
                float2 w = *reinterpret_cast<const float2*>(wB + (k0+kk)*256 + cp);
                #pragma unroll
                for (int u=0;u<8;u++){
                    float x = elem(xv[u],kk);
                    qr0[u] = fmaf(x, w.x, qr0[u]);
                    qr1[u] = fmaf(x, w.y, qr1[u]);
                }
            }
        }
        float2 w2v = *reinterpret_cast<const float2*>(W2 + cp);
        #pragma unroll
        for (int u=0;u<8;u++) sq[u] = qr0[u]*w2v.x + qr1[u]*w2v.y;
        #pragma unroll
        for (int d=1; d<64; d<<=1){
            #pragma unroll
            for (int u=0;u<8;u++) sq[u] += __shfl_xor(sq[u], d);
        }
    }

    // ---- P1 (MFMA dual): q1 = st@Wqp -> B1, k1 = st@Wkp -> B2 ----
    {
        f32x4v aq0={0.f,0.f,0.f,0.f}, aq1={0.f,0.f,0.f,0.f};
        f32x4v ak0={0.f,0.f,0.f,0.f}, ak1={0.f,0.f,0.f,0.f};
        const unsigned short* ab = Xoa + arow*168 + (l>>4)*8;
        #pragma unroll
        for (int kt = 0; kt < 4; kt++){
            bf16x8 a   = *reinterpret_cast<const bf16x8*>(ab + kt*32);
            bf16x8 bq0 = *reinterpret_cast<const bf16x8*>(Wqps + (size_t)((kt*8+ntb  )*64 + l)*8);
            bf16x8 bq1 = *reinterpret_cast<const bf16x8*>(Wqps + (size_t)((kt*8+ntb+1)*64 + l)*8);
            bf16x8 bk0 = *reinterpret_cast<const bf16x8*>(Wkps + (size_t)((kt*8+ntb  )*64 + l)*8);
            bf16x8 bk1 = *reinterpret_cast<const bf16x8*>(Wkps + (size_t)((kt*8+ntb+1)*64 + l)*8);
            aq0 = mfma16(a, bq0, aq0); aq1 = mfma16(a, bq1, aq1);
            ak0 = mfma16(a, bk0, ak0); ak1 = mfma16(a, bk1, ak1);
        }
        #pragma unroll
        for (int r = 0; r < 4; r++){
            B1[(drow+r)*132 + ntb*16     + dcol] = aq0[r];
            B1[(drow+r)*132 + (ntb+1)*16 + dcol] = aq1[r];
            B2[(drow+r)*132 + ntb*16     + dcol] = ak0[r];
            B2[(drow+r)*132 + (ntb+1)*16 + dcol] = ak1[r];
        }
    }

    // ---- A1-hoist (MFMA): ac = [st|act|0]@WAB (K=160), regs until post-sm2 ----
    f32x4v ac[4];
    {
        #pragma unroll
        for (int n=0;n<4;n++) ac[n] = f32x4v{0.f,0.f,0.f,0.f};
        const unsigned short* ab = Xoa + arow*168 + (l>>4)*8;
        #pragma unroll
        for (int kt = 0; kt < 5; kt++){
            bf16x8 a = *reinterpret_cast<const bf16x8*>(ab + kt*32);
            #pragma unroll
            for (int n = 0; n < 4; n++){
                bf16x8 bb = *reinterpret_cast<const bf16x8*>(WABs + (size_t)((kt*16 + nb7 + n)*64 + l)*8);
                ac[n] = mfma16(a, bb, ac[n]);
            }
        }
    }
    __syncthreads();

    // ---- P2: w1 = softmax(q1@k1^T * scale) ----
    scores_softmax512(B1, B2, scale, Wb1f, out_w1 + (size_t)b*1024, si, sj);
    __syncthreads();

    // ---- P3 (VALU): u = w1@st -> Ubf (bf16, over B1) ----
    {
        float au[8];
        #pragma unroll
        for (int u=0;u<8;u++) au[u]=0.f;
        #pragma unroll
        for (int k0=0;k0<32;k0+=4){
            float4 xv[8];
            #pragma unroll
            for (int u=0;u<8;u++) xv[u] = ld4(Wb1f + (g*8+u)*36 + k0);
            #pragma unroll
            for (int kk=0;kk<4;kk++){
                float w = bf2f(Xoa[(k0+kk)*168 + c]);
                #pragma unroll
                for (int u=0;u<8;u++) au[u] = fmaf(elem(xv[u],kk), w, au[u]);
            }
        }
        #pragma unroll
        for (int u=0;u<8;u++) Ubf[(g*8+u)*136 + c] = (unsigned short)f2bf(au[u]);
    }
    __syncthreads();

    // ---- P4 (MFMA): wav1 = u@Wvp -> Wvbf (bf16, over B2) ----
    {
        f32x4v av0={0.f,0.f,0.f,0.f}, av1={0.f,0.f,0.f,0.f};
        const unsigned short* ab = Ubf + arow*136 + (l>>4)*8;
        #pragma unroll
        for (int kt = 0; kt < 4; kt++){
            bf16x8 a  = *reinterpret_cast<const bf16x8*>(ab + kt*32);
            bf16x8 b0 = *reinterpret_cast<const bf16x8*>(Wvps + (size_t)((kt*8+ntb  )*64 + l)*8);
            bf16x8 b1 = *reinterpret_cast<const bf16x8*>(Wvps + (size_t)((kt*8+ntb+1)*64 + l)*8);
            av0 = mfma16(a, b0, av0); av1 = mfma16(a, b1, av1);
        }
        #pragma unroll
        for (int r = 0; r < 4; r++){
            Wvbf[(drow+r)*136 + ntb*16     + dcol] = (unsigned short)f2bf(av0[r]);
            Wvbf[(drow+r)*136 + (ntb+1)*16 + dcol] = (unsigned short)f2bf(av1[r]);
        }
    }
    __syncthreads();

    // ---- P5 (MFMA dual): q2 = wav1@Wq, k2 = wav1@Wk -> regs -> B1,B2 ----
    {
        f32x4v aq0={0.f,0.f,0.f,0.f}, aq1={0.f,0.f,0.f,0.f};
        f32x4v ak0={0.f,0.f,0.f,0.f}, ak1={0.f,0.f,0.f,0.f};
        const unsigned short* ab = Wvbf + arow*136 + (l>>4)*8;
        #pragma unroll
        for (int kt = 0; kt < 4; kt++){
            bf16x8 a   = *reinterpret_cast<const bf16x8*>(ab + kt*32);
            bf16x8 bq0 = *reinterpret_cast<const bf16x8*>(Wqs + (size_t)((kt*8+ntb  )*64 + l)*8);
            bf16x8 bq1 = *reinterpret_cast<const bf16x8*>(Wqs + (size_t)((kt*8+ntb+1)*64 + l)*8);
            bf16x8 bk0 = *reinterpret_cast<const bf16x8*>(Wks + (size_t)((kt*8+ntb  )*64 + l)*8);
            bf16x8 bk1 = *reinterpret_cast<const bf16x8*>(Wks + (size_t)((kt*8+ntb+1)*64 + l)*8);
            aq0 = mfma16(a, bq0, aq0); aq1 = mfma16(a, bq1, aq1);
            ak0 = mfma16(a, bk0, ak0); ak1 = mfma16(a, bk1, ak1);
        }
        __syncthreads();   // everyone done reading Wvbf
        #pragma unroll
        for (int r = 0; r < 4; r++){
            B1[(drow+r)*132 + ntb*16     + dcol] = aq0[r];
            B1[(drow+r)*132 + (ntb+1)*16 + dcol] = aq1[r];
            B2[(drow+r)*132 + ntb*16     + dcol] = ak0[r];
            B2[(drow+r)*132 + (ntb+1)*16 + dcol] = ak1[r];
        }
    }
    __syncthreads();

    // ---- P6: w2 = softmax(q2@k2^T * scale) ----
    scores_softmax512(B1, B2, scale, Wb2f, out_w2 + (size_t)b*1024, si, sj);
    __syncthreads();

    // ---- A1 store (over dead B1/B2) ----
    {
        #pragma unroll
        for (int n = 0; n < 4; n++){
            #pragma unroll
            for (int r = 0; r < 4; r++)
                A1[(drow+r)*260 + (nb7+n)*16 + dcol] = ac[n][r];
        }
    }
    __syncthreads();

    // ---- P8 (VALU): P = w2@A1 (K=32) -> bf16 P2 (over dead Xoa) + SP ----
    {
        float ap0[8], ap1[8];
        #pragma unroll
        for (int u=0;u<8;u++){ ap0[u]=0.f; ap1[u]=0.f; }
        #pragma unroll
        for (int k0=0;k0<32;k0+=4){
            float4 xv[8];
            #pragma unroll
            for (int u=0;u<8;u++) xv[u] = ld4(Wb2f + (g*8+u)*36 + k0);
            #pragma unroll
            for (int kk=0;kk<4;kk++){
                float2 w = *reinterpret_cast<const float2*>(A1 + (k0+kk)*260 + cp);
                #pragma unroll
                for (int u=0;u<8;u++){
                    float x = elem(xv[u],kk);
                    ap0[u] = fmaf(x, w.x, ap0[u]);
                    ap1[u] = fmaf(x, w.y, ap1[u]);
                }
            }
        }
        #pragma unroll
        for (int u=0;u<8;u++)
            P2[(g*8+u)*128 + (cp>>1)] = pack2(ap0[u], ap1[u]);
        // SP[row] = sum_h W2[h]*P[row][h]: per-lane partial + wave butterfly
        float2 w2v = *reinterpret_cast<const float2*>(W2 + cp);
        float sp[8];
        #pragma unroll
        for (int u=0;u<8;u++) sp[u] = ap0[u]*w2v.x + ap1[u]*w2v.y;
        #pragma unroll
        for (int d=1; d<64; d<<=1){
            #pragma unroll
            for (int u=0;u<8;u++) sp[u] += __shfl_xor(sp[u], d);
        }
        if (l == 0){
            #pragma unroll
            for (int u=0;u<8;u++) SPQ[(g*8+u)*2 + wp] = sp[u];
        }
    }
    __syncthreads();

    // ---- Q2 store (over dead A1) + SQ partials ----
    {
        #pragma unroll
        for (int u=0;u<8;u++)
            Q2[(g*8+u)*132 + (cp>>1)] = pack2(qr0[u], qr1[u]);
        if (l == 0){
            #pragma unroll
            for (int u=0;u<8;u++) SPQ[64 + (g*8+u)*2 + wp] = sq[u];
        }
    }
    __syncthreads();

    // ---- P10: value[i,j] = 0.505*(SP[i]+w*SQ[j]) + 0.495*sum_h W2[h]*|..| ----
    {
        float w00 = Wb2f[si*36 + sj], w01 = Wb2f[si*36 + sj + 16];
        float SPi = SPQ[si*2] + SPQ[si*2+1];
        float SQa = SPQ[64 + sj*2] + SPQ[64 + sj*2+1];
        float SQb = SPQ[64 + (sj+16)*2] + SPQ[64 + (sj+16)*2+1];
        float a0 = 0.f, a1 = 0.f;

        #define PROC(PA,QA,QB,H2) {                                         \
            float w2e = W2[(H2)], w2o = W2[(H2)+1];                         \
            float paE = __uint_as_float((PA)<<16), paO = __uint_as_float((PA) & 0xffff0000u); \
            float qaE = __uint_as_float((QA)<<16), qaO = __uint_as_float((QA) & 0xffff0000u); \
            float qbE = __uint_as_float((QB)<<16), qbO = __uint_as_float((QB) & 0xffff0000u); \
            float t0 = fmaf(w00, qaE, paE); a0 = fmaf(fabsf(t0), w2e, a0);  \
            float t1 = fmaf(w00, qaO, paO); a0 = fmaf(fabsf(t1), w2o, a0);  \
            float t2 = fmaf(w01, qbE, paE); a1 = fmaf(fabsf(t2), w2e, a1);  \
            float t3 = fmaf(w01, qbO, paO); a1 = fmaf(fabsf(t3), w2o, a1); }

        #pragma unroll 4
        for (int hp4 = 0; hp4 < 32; hp4++){
            uint4 pa4 = *reinterpret_cast<const uint4*>(P2 + si*128 + hp4*4);
            uint4 qa4 = *reinterpret_cast<const uint4*>(Q2 + sj*132 + hp4*4);
            uint4 qb4 = *reinterpret_cast<const uint4*>(Q2 + (sj+16)*132 + hp4*4);
            PROC(pa4.x, qa4.x, qb4.x, hp4*8+0)
            PROC(pa4.y, qa4.y, qb4.y, hp4*8+2)
            PROC(pa4.z, qa4.z, qb4.z, hp4*8+4)
            PROC(pa4.w, qa4.w, qb4.w, hp4*8+6)
        }
        #undef PROC

        float* ov = out_v + (size_t)b*1024;
        ov[si*32 + sj]      = fmaf(0.495f, a0, 0.505f*(SPi + w00*SQa));
        ov[si*32 + sj + 16] = fmaf(0.495f, a1, 0.505f*(SPi + w01*SQb));
    }
}

extern "C" void kernel_launch(void* const* d_in, const int* in_sizes, int n_in,
                              void* d_out, int out_size, void* d_ws, size_t ws_size,
                              hipStream_t stream) {
    const float* states = (const float*)d_in[0];
    const float* pol    = (const float*)d_in[1];
    const float* act    = (const float*)d_in[2];
    const float* Wkp    = (const float*)d_in[3];
    const float* Wqp    = (const float*)d_in[4];
    const float* Wvp    = (const float*)d_in[5];
    const float* Wk     = (const float*)d_in[6];
    const float* Wq     = (const float*)d_in[7];
    const float* We     = (const float*)d_in[8];
    const float* Wav    = (const float*)d_in[9];
    const float* W1     = (const float*)d_in[10];
    const float* W2     = (const float*)d_in[11];

    float* out    = (float*)d_out;
    float* out_v  = out;                 // [256,32,32,1]
    float* out_w1 = out + 256*1024;      // [256,32,32]
    float* out_w2 = out + 2*256*1024;    // [256,32,32]

    // workspace layout (floats)
    float* WABf = (float*)d_ws;                                  // [144][256] fp32 (rows 128..143 used)
    unsigned short* WABs = (unsigned short*)(WABf + 36864);      // 80 frags * 512 = 40960 ush
    unsigned short* wsu  = (unsigned short*)(WABf + 57344);
    unsigned short* Wqps = wsu;             // 32 frags * 512 = 16384 ush each
    unsigned short* Wkps = wsu + 16384;
    unsigned short* Wvps = wsu + 32768;
    unsigned short* Wqs  = wsu + 49152;
    unsigned short* Wks  = wsu + 65536;
    float* T2g = WABf + 98304;              // [128][256] fp32

    hipLaunchKernelGGL(k_pre0, dim3(52), dim3(512), 0, stream,
                       Wav, W1, Wqp, Wkp, Wvp, Wq, Wk,
                       T2g, Wqps, Wkps, Wvps, Wqs, Wks);
    hipLaunchKernelGGL(k_pre1, dim3(16), dim3(512), 0, stream,
                       We, T2g, WABf, WABs);
    hipLaunchKernelGGL(k_main, dim3(NB), dim3(512), 0, stream,
                       states, pol, act,
                       Wqps, Wkps, Wvps, Wqs, Wks, WABs, WABf, W2,
                       out_v, out_w1, out_w2);
}

// Round 9
// 44.265 us; speedup vs baseline: 1.0355x; 1.0355x over previous
//
#include <hip/hip_runtime.h>
#include <math.h>

// Problem constants
#define NB 256   // batches
#define NN 32    // agents
#define DD 128   // state dim
#define NA 16    // action dim
#define HH 256   // hidden

using f32x4v  = __attribute__((ext_vector_type(4))) float;
using bf16x8  = __attribute__((ext_vector_type(8))) short;

static __device__ __forceinline__ float4 ld4(const float* p){ return *reinterpret_cast<const float4*>(p); }
static __device__ __forceinline__ void st4f(float* p, float4 v){ *reinterpret_cast<float4*>(p) = v; }
static __device__ __forceinline__ float elem(float4 v, int kk){
    return (kk==0)?v.x:(kk==1)?v.y:(kk==2)?v.z:v.w;
}

static __device__ __forceinline__ unsigned f2bf(float x){
    unsigned u = __float_as_uint(x);
    u += 0x7fffu + ((u >> 16) & 1u);   // round-to-nearest-even
    return u >> 16;
}
static __device__ __forceinline__ unsigned pack2(float a, float b){
    return f2bf(a) | (f2bf(b) << 16);
}
static __device__ __forceinline__ float bf2f(unsigned short s){
    return __uint_as_float(((unsigned)s) << 16);
}

static __device__ __forceinline__ f32x4v mfma16(bf16x8 a, bf16x8 b, f32x4v c){
    return __builtin_amdgcn_mfma_f32_16x16x32_bf16(a, b, c, 0, 0, 0);
}

// write one B-fragment (16 bf16 bytes per lane) to the swizzled weight buffer
static __device__ __forceinline__ void store_frag(unsigned short* __restrict__ dst,
                                                  int frag, int l, const float v[8]){
    uint4 p;
    p.x = pack2(v[0], v[1]); p.y = pack2(v[2], v[3]);
    p.z = pack2(v[4], v[5]); p.w = pack2(v[6], v[7]);
    *reinterpret_cast<uint4*>(dst + (size_t)(frag*64 + l)*8) = p;
}

// =============================================================================
// k_pre (36 blocks x 512), single launch:
//   blocks 0..15 : col tile ct of WAB = We @ (Wav @ W1).
//     Phase A: T2[:,16] = Wav @ W1[:,ct*16..] (W1 slice transposed in LDS,
//              Wav staged in 64-row chunks, padded pitches -> conflict-free).
//     Phase B: WAB tile = We @ T2 (We staged in 48-row chunks). Emits bf16
//              frags (kt 0..4, nt=ct; rows 144..159 zero) + fp32 rows
//              128..143 -> WABf.
//   blocks 16..35: fragment-swizzled bf16 copies of the 5 attention weights.
// Fragment layout (16x16x32 B-frag): frag (kt,nt): lane l holds
//   B[kt*32+(l>>4)*8+i][nt*16+(l&15)], i=0..7.
// =============================================================================
__global__ __launch_bounds__(512)
void k_pre(const float* __restrict__ We, const float* __restrict__ Wav,
           const float* __restrict__ W1,
           const float* __restrict__ Wqp, const float* __restrict__ Wkp,
           const float* __restrict__ Wvp, const float* __restrict__ Wq,
           const float* __restrict__ Wk,
           float* __restrict__ WABf, unsigned short* __restrict__ WABs,
           unsigned short* __restrict__ Wqps, unsigned short* __restrict__ Wkps,
           unsigned short* __restrict__ Wvps, unsigned short* __restrict__ Wqs,
           unsigned short* __restrict__ Wks)
{
    __shared__ float SH[15232];      // 60.9 KB
    float* W1t  = SH;                // [16][132] transposed W1 slice
    float* T2c  = SH + 2112;         // [16][132] transposed T2 slice
    float* BUF  = SH + 4224;         // WavC [64][132] / WeC [48][132]
    float* WABt = SH + 12672;        // [160][16]

    const int t = threadIdx.x;
    const int bid = blockIdx.x;

    if (bid < 16) {
        const int ct = bid;

        // stage W1 slice transposed: W1t[c][k]
        {
            int row = t >> 2, c4 = (t & 3) * 4;
            float4 v = ld4(W1 + (size_t)row*256 + ct*16 + c4);
            W1t[(c4+0)*132 + row] = v.x;
            W1t[(c4+1)*132 + row] = v.y;
            W1t[(c4+2)*132 + row] = v.z;
            W1t[(c4+3)*132 + row] = v.w;
        }
        // zero-pad WABt rows 144..159 (region untouched until phase B writes)
        if (t < 256) WABt[(144 + (t>>4))*16 + (t&15)] = 0.f;

        // ---- Phase A: T2[m][c] = sum_k Wav[m][k]*W1t[c][k], 2 chunks of 64 rows
        const int ml  = t >> 3;          // 0..63
        const int cpr = (t & 7) * 2;     // col pair
        for (int ch = 0; ch < 2; ch++) {
            __syncthreads();   // W1t staged (ch=0) / prev chunk reads done
            #pragma unroll
            for (int u = 0; u < 4; u++) {
                int idx = t + 512*u;             // float4 idx 0..2047
                int row = idx >> 5, c4 = (idx & 31) * 4;
                st4f(BUF + row*132 + c4, ld4(Wav + (size_t)(ch*64 + row)*128 + c4));
            }
            __syncthreads();
            float a0 = 0.f, a1 = 0.f;
            #pragma unroll 4
            for (int k0 = 0; k0 < 128; k0 += 4) {
                float4 wa = ld4(BUF + ml*132 + k0);
                float4 t0 = ld4(W1t + cpr*132 + k0);
                float4 t1 = ld4(W1t + (cpr+1)*132 + k0);
                #pragma unroll
                for (int kk = 0; kk < 4; kk++) {
                    float x = elem(wa, kk);
                    a0 = fmaf(x, elem(t0,kk), a0);
                    a1 = fmaf(x, elem(t1,kk), a1);
                }
            }
            T2c[cpr*132 + ch*64 + ml]     = a0;
            T2c[(cpr+1)*132 + ch*64 + ml] = a1;
        }

        // ---- Phase B: WAB[r][c] = sum_k We[r][k]*T2c[c][k], 3 chunks of 48 rows
        const int rg = t >> 4;   // 0..31
        const int c  = t & 15;
        for (int c3 = 0; c3 < 3; c3++) {
            const int rows48 = c3 * 48;
            __syncthreads();   // T2c writes done (c3=0) / prev WeC reads done
            #pragma unroll
            for (int u = 0; u < 3; u++) {
                int idx = t + 512*u;             // float4 idx 0..1535
                int row = idx >> 5, c4 = (idx & 31) * 4;
                st4f(BUF + row*132 + c4, ld4(We + (size_t)(rows48 + row)*128 + c4));
            }
            __syncthreads();
            float accA = 0.f, accB = 0.f;
            #pragma unroll 4
            for (int k0 = 0; k0 < 128; k0 += 4) {
                float4 wa = ld4(BUF + rg*132 + k0);
                float4 wb = ld4(BUF + (rg+32)*132 + k0);
                float4 tv = ld4(T2c + c*132 + k0);
                #pragma unroll
                for (int kk = 0; kk < 4; kk++) {
                    float tvk = elem(tv, kk);
                    accA = fmaf(elem(wa,kk), tvk, accA);
                    accB = fmaf(elem(wb,kk), tvk, accB);
                }
            }
            WABt[(rows48 + rg)*16 + c] = accA;
            if (rg < 16) {
                WABt[(rows48 + rg + 32)*16 + c] = accB;
                if (c3 == 2)   // global rows 128..143
                    WABf[(size_t)(128 + rg)*256 + ct*16 + c] = accB;
            }
        }
        __syncthreads();

        // swizzle-emit 5 frags (kt=0..4, nt=ct)
        if (t < 320) {
            int kt = t >> 6, l = t & 63;
            float v[8];
            #pragma unroll
            for (int i = 0; i < 8; i++)
                v[i] = WABt[(kt*32 + (l>>4)*8 + i)*16 + (l&15)];
            store_frag(WABs, kt*16 + ct, l, v);
        }
    } else {
        // 8 frags per block; 160 frags = 5 weights x 32
        const int bb = bid - 16;
        const int fg = bb*8 + (t >> 6);
        const int l  = t & 63;
        const int sel = fg >> 5, frag = fg & 31;
        const int kt = frag >> 3, nt = frag & 7;
        const float* W = (sel==0) ? Wqp : (sel==1) ? Wkp : (sel==2) ? Wvp :
                         (sel==3) ? Wq : Wk;
        unsigned short* dst = (sel==0) ? Wqps : (sel==1) ? Wkps : (sel==2) ? Wvps :
                              (sel==3) ? Wqs : Wks;
        float v[8];
        #pragma unroll
        for (int i = 0; i < 8; i++)
            v[i] = W[(kt*32 + (l>>4)*8 + i)*128 + nt*16 + (l&15)];
        store_frag(dst, frag, l, v);
    }
}

// scores+softmax, 512 threads: thread (i=t>>4, j=t&15) covers (i,j) and (i,j+16).
static __device__ __forceinline__ void scores_softmax512(const float* __restrict__ Qm,
                                                         const float* __restrict__ Km,
                                                         float scale,
                                                         float* __restrict__ w_lds,
                                                         float* __restrict__ w_out,
                                                         int i, int j)
{
    float s0 = 0.f, s1 = 0.f;
    #pragma unroll 4
    for (int k=0;k<128;k+=4){
        float4 qv = ld4(Qm + i*132 + k);
        float4 k0 = ld4(Km + j*132 + k);
        float4 k1 = ld4(Km + (j+16)*132 + k);
        s0 += qv.x*k0.x + qv.y*k0.y + qv.z*k0.z + qv.w*k0.w;
        s1 += qv.x*k1.x + qv.y*k1.y + qv.z*k1.z + qv.w*k1.w;
    }
    s0 *= scale; s1 *= scale;
    float m = fmaxf(s0, s1);
    #pragma unroll
    for (int d=1; d<16; d<<=1) m = fmaxf(m, __shfl_xor(m, d));
    float e0 = expf(s0 - m), e1 = expf(s1 - m);
    float sum = e0 + e1;
    #pragma unroll
    for (int d=1; d<16; d<<=1) sum += __shfl_xor(sum, d);
    float inv = 1.f / sum;
    e0 *= inv; e1 *= inv;
    w_lds[i*36 + j]      = e0;
    w_lds[i*36 + j + 16] = e1;
    w_out[i*32 + j]      = e0;
    w_out[i*32 + j + 16] = e1;
}

// =============================================================================
// k_main: one block per batch, 512 threads (8 waves). R6 phase order (no
// register hoists) + P10 linear/abs split via SP/SQ reductions.
// =============================================================================
__global__ __launch_bounds__(512)
void k_main(const float* __restrict__ states, const float* __restrict__ pol,
            const float* __restrict__ act,
            const unsigned short* __restrict__ Wqps, const unsigned short* __restrict__ Wkps,
            const unsigned short* __restrict__ Wvps, const unsigned short* __restrict__ Wqs,
            const unsigned short* __restrict__ Wks,  const unsigned short* __restrict__ WABs,
            const float* __restrict__ WABf, const float* __restrict__ W2,
            float* __restrict__ out_v, float* __restrict__ out_w1,
            float* __restrict__ out_w2)
{
    const int b = blockIdx.x;
    const int t = threadIdx.x;
    const float scale = 0.08838834764831845f;  // 1/sqrt(128)

    __shared__ float SH[16000];   // 62.5 KB
    float* B1   = SH;                                   // 32x132
    float* B2   = SH + 4224;                            // 32x132
    float* Wb2f = SH + 8448;                            // 32x36
    float* Wb1f = SH + 9600;                            // 32x36
    float* APd  = SH + 10752;                           // 32x16 (pol-act)
    unsigned short* Xoa  = (unsigned short*)(SH + 11264); // [32][168] bf16 (st|act|0)
    unsigned short* Ubf  = (unsigned short*)B1;           // [32][136] bf16
    unsigned short* Wvbf = (unsigned short*)B2;           // [32][136] bf16
    float*    A1 = SH;                                   // [32][260] fp32 (over B1+B2)
    unsigned* P2 = (unsigned*)(SH + 11904);              // [32][128] packed bf16 (over dead Xoa)
    unsigned* Q2 = (unsigned*)SH;                        // [32][132] packed bf16 (over dead A1)
    float* SPQ = Wb1f;   // SP[32][2] at 0, SQ[32][2] at +64 (Wb1f dead after P3)

    const float* stg  = states + (size_t)b*(NN*DD);
    const float* actg = act + (size_t)b*(NN*NA);
    const float* polg = pol + (size_t)b*(NN*NA);

    // ---- stage Xoa = bf16([st | act | 0]) (k 0..159), APd = pol-act ----
    {
        int r = t >> 4, kb = t & 15;
        #pragma unroll
        for (int uu = 0; uu < 10; uu++){
            int k = kb + 16*uu;
            float v = (k < 128) ? stg[r*128 + k]
                    : (k < 144) ? actg[r*16 + (k-128)] : 0.f;
            Xoa[r*168 + k] = (unsigned short)f2bf(v);
        }
        if (t < 128) {
            int rr = t>>2, cc = (t&3)*4;
            float4 p = ld4(polg + rr*16 + cc), a = ld4(actg + rr*16 + cc);
            st4f(APd + rr*16 + cc, make_float4(p.x-a.x, p.y-a.y, p.z-a.z, p.w-a.w));
        }
    }
    __syncthreads();

    // MFMA wave geometry
    const int l    = t & 63;
    const int wv   = t >> 6;             // wave 0..7
    const int mt   = wv & 1;             // M-tile
    const int ntb  = (wv >> 1) * 2;      // N-tile base (128-col GEMMs)
    const int nb7  = (wv >> 1) * 4;      // N-tile base (256-col GEMM)
    const int arow = mt*16 + (l & 15);
    const int drow = mt*16 + ((l >> 4) << 2);
    const int dcol = l & 15;

    // VALU phase geometry
    const int c  = t & 127;
    const int g  = t >> 7;
    const int cp = (t & 127)*2;
    const int si = t >> 4;
    const int sj = t & 15;
    const int wp = wv & 1;

    // ---- P1 (MFMA dual): q1 = st@Wqp -> B1, k1 = st@Wkp -> B2 ----
    {
        f32x4v aq0={0.f,0.f,0.f,0.f}, aq1={0.f,0.f,0.f,0.f};
        f32x4v ak0={0.f,0.f,0.f,0.f}, ak1={0.f,0.f,0.f,0.f};
        const unsigned short* ab = Xoa + arow*168 + (l>>4)*8;
        #pragma unroll
        for (int kt = 0; kt < 4; kt++){
            bf16x8 a   = *reinterpret_cast<const bf16x8*>(ab + kt*32);
            bf16x8 bq0 = *reinterpret_cast<const bf16x8*>(Wqps + (size_t)((kt*8+ntb  )*64 + l)*8);
            bf16x8 bq1 = *reinterpret_cast<const bf16x8*>(Wqps + (size_t)((kt*8+ntb+1)*64 + l)*8);
            bf16x8 bk0 = *reinterpret_cast<const bf16x8*>(Wkps + (size_t)((kt*8+ntb  )*64 + l)*8);
            bf16x8 bk1 = *reinterpret_cast<const bf16x8*>(Wkps + (size_t)((kt*8+ntb+1)*64 + l)*8);
            aq0 = mfma16(a, bq0, aq0); aq1 = mfma16(a, bq1, aq1);
            ak0 = mfma16(a, bk0, ak0); ak1 = mfma16(a, bk1, ak1);
        }
        #pragma unroll
        for (int r = 0; r < 4; r++){
            B1[(drow+r)*132 + ntb*16     + dcol] = aq0[r];
            B1[(drow+r)*132 + (ntb+1)*16 + dcol] = aq1[r];
            B2[(drow+r)*132 + ntb*16     + dcol] = ak0[r];
            B2[(drow+r)*132 + (ntb+1)*16 + dcol] = ak1[r];
        }
    }
    __syncthreads();

    // ---- P2: w1 = softmax(q1@k1^T * scale) ----
    scores_softmax512(B1, B2, scale, Wb1f, out_w1 + (size_t)b*1024, si, sj);
    __syncthreads();

    // ---- P3 (VALU): u = w1@st -> Ubf (bf16, over B1) ----
    {
        float au[8];
        #pragma unroll
        for (int u=0;u<8;u++) au[u]=0.f;
        #pragma unroll
        for (int k0=0;k0<32;k0+=4){
            float4 xv[8];
            #pragma unroll
            for (int u=0;u<8;u++) xv[u] = ld4(Wb1f + (g*8+u)*36 + k0);
            #pragma unroll
            for (int kk=0;kk<4;kk++){
                float w = bf2f(Xoa[(k0+kk)*168 + c]);
                #pragma unroll
                for (int u=0;u<8;u++) au[u] = fmaf(elem(xv[u],kk), w, au[u]);
            }
        }
        __syncthreads();   // B1/scores traffic done before bf16 overwrite
        #pragma unroll
        for (int u=0;u<8;u++) Ubf[(g*8+u)*136 + c] = (unsigned short)f2bf(au[u]);
    }
    __syncthreads();

    // ---- P4 (MFMA): wav1 = u@Wvp -> Wvbf (bf16, over B2) ----
    {
        f32x4v av0={0.f,0.f,0.f,0.f}, av1={0.f,0.f,0.f,0.f};
        const unsigned short* ab = Ubf + arow*136 + (l>>4)*8;
        #pragma unroll
        for (int kt = 0; kt < 4; kt++){
            bf16x8 a  = *reinterpret_cast<const bf16x8*>(ab + kt*32);
            bf16x8 b0 = *reinterpret_cast<const bf16x8*>(Wvps + (size_t)((kt*8+ntb  )*64 + l)*8);
            bf16x8 b1 = *reinterpret_cast<const bf16x8*>(Wvps + (size_t)((kt*8+ntb+1)*64 + l)*8);
            av0 = mfma16(a, b0, av0); av1 = mfma16(a, b1, av1);
        }
        #pragma unroll
        for (int r = 0; r < 4; r++){
            Wvbf[(drow+r)*136 + ntb*16     + dcol] = (unsigned short)f2bf(av0[r]);
            Wvbf[(drow+r)*136 + (ntb+1)*16 + dcol] = (unsigned short)f2bf(av1[r]);
        }
    }
    __syncthreads();

    // ---- P5 (MFMA dual): q2 = wav1@Wq, k2 = wav1@Wk -> regs -> B1,B2 ----
    {
        f32x4v aq0={0.f,0.f,0.f,0.f}, aq1={0.f,0.f,0.f,0.f};
        f32x4v ak0={0.f,0.f,0.f,0.f}, ak1={0.f,0.f,0.f,0.f};
        const unsigned short* ab = Wvbf + arow*136 + (l>>4)*8;
        #pragma unroll
        for (int kt = 0; kt < 4; kt++){
            bf16x8 a   = *reinterpret_cast<const bf16x8*>(ab + kt*32);
            bf16x8 bq0 = *reinterpret_cast<const bf16x8*>(Wqs + (size_t)((kt*8+ntb  )*64 + l)*8);
            bf16x8 bq1 = *reinterpret_cast<const bf16x8*>(Wqs + (size_t)((kt*8+ntb+1)*64 + l)*8);
            bf16x8 bk0 = *reinterpret_cast<const bf16x8*>(Wks + (size_t)((kt*8+ntb  )*64 + l)*8);
            bf16x8 bk1 = *reinterpret_cast<const bf16x8*>(Wks + (size_t)((kt*8+ntb+1)*64 + l)*8);
            aq0 = mfma16(a, bq0, aq0); aq1 = mfma16(a, bq1, aq1);
            ak0 = mfma16(a, bk0, ak0); ak1 = mfma16(a, bk1, ak1);
        }
        __syncthreads();   // everyone done reading Wvbf
        #pragma unroll
        for (int r = 0; r < 4; r++){
            B1[(drow+r)*132 + ntb*16     + dcol] = aq0[r];
            B1[(drow+r)*132 + (ntb+1)*16 + dcol] = aq1[r];
            B2[(drow+r)*132 + ntb*16     + dcol] = ak0[r];
            B2[(drow+r)*132 + (ntb+1)*16 + dcol] = ak1[r];
        }
    }
    __syncthreads();

    // ---- P6: w2 = softmax(q2@k2^T * scale) ----
    scores_softmax512(B1, B2, scale, Wb2f, out_w2 + (size_t)b*1024, si, sj);
    __syncthreads();

    // ---- P7 (MFMA): A1 = [st|act|0]@WAB (K=160, N=256) -> A1 (over B1/B2) ----
    {
        f32x4v ac[4];
        #pragma unroll
        for (int n=0;n<4;n++) ac[n] = f32x4v{0.f,0.f,0.f,0.f};
        const unsigned short* ab = Xoa + arow*168 + (l>>4)*8;
        #pragma unroll
        for (int kt = 0; kt < 5; kt++){
            bf16x8 a = *reinterpret_cast<const bf16x8*>(ab + kt*32);
            #pragma unroll
            for (int n = 0; n < 4; n++){
                bf16x8 bb = *reinterpret_cast<const bf16x8*>(WABs + (size_t)((kt*16 + nb7 + n)*64 + l)*8);
                ac[n] = mfma16(a, bb, ac[n]);
            }
        }
        #pragma unroll
        for (int n = 0; n < 4; n++){
            #pragma unroll
            for (int r = 0; r < 4; r++)
                A1[(drow+r)*260 + (nb7+n)*16 + dcol] = ac[n][r];
        }
    }
    __syncthreads();

    // ---- P8 (VALU): P = w2@A1 (K=32) -> bf16 P2 (over dead Xoa) + SP ----
    {
        float ap0[8], ap1[8];
        #pragma unroll
        for (int u=0;u<8;u++){ ap0[u]=0.f; ap1[u]=0.f; }
        #pragma unroll
        for (int k0=0;k0<32;k0+=4){
            float4 xv[8];
            #pragma unroll
            for (int u=0;u<8;u++) xv[u] = ld4(Wb2f + (g*8+u)*36 + k0);
            #pragma unroll
            for (int kk=0;kk<4;kk++){
                float2 w = *reinterpret_cast<const float2*>(A1 + (k0+kk)*260 + cp);
                #pragma unroll
                for (int u=0;u<8;u++){
                    float x = elem(xv[u],kk);
                    ap0[u] = fmaf(x, w.x, ap0[u]);
                    ap1[u] = fmaf(x, w.y, ap1[u]);
                }
            }
        }
        __syncthreads();  // A1/Xoa reads done before P2 overwrite
        #pragma unroll
        for (int u=0;u<8;u++)
            P2[(g*8+u)*128 + (cp>>1)] = pack2(ap0[u], ap1[u]);
        // SP[row] = sum_h W2[h]*P[row][h]: per-lane partial + wave butterfly
        float2 w2v = *reinterpret_cast<const float2*>(W2 + cp);
        float sp[8];
        #pragma unroll
        for (int u=0;u<8;u++) sp[u] = ap0[u]*w2v.x + ap1[u]*w2v.y;
        #pragma unroll
        for (int d=1; d<64; d<<=1){
            #pragma unroll
            for (int u=0;u<8;u++) sp[u] += __shfl_xor(sp[u], d);
        }
        if (l == 0){
            #pragma unroll
            for (int u=0;u<8;u++) SPQ[(g*8+u)*2 + wp] = sp[u];
        }
    }
    __syncthreads();

    // ---- P9 (VALU): Q = (pol-act)@WB (K=16) -> bf16 Q2 (over dead A1) + SQ ----
    {
        float aq0[8], aq1[8];
        #pragma unroll
        for (int u=0;u<8;u++){ aq0[u]=0.f; aq1[u]=0.f; }
        const float* wB = WABf + 128*256;
        #pragma unroll
        for (int k0=0;k0<16;k0+=4){
            float4 xv[8];
            #pragma unroll
            for (int u=0;u<8;u++) xv[u] = ld4(APd + (g*8+u)*16 + k0);
            #pragma unroll
            for (int kk=0;kk<4;kk++){
                float2 w = *reinterpret_cast<const float2*>(wB + (k0+kk)*256 + cp);
                #pragma unroll
                for (int u=0;u<8;u++){
                    float x = elem(xv[u],kk);
                    aq0[u] = fmaf(x, w.x, aq0[u]);
                    aq1[u] = fmaf(x, w.y, aq1[u]);
                }
            }
        }
        #pragma unroll
        for (int u=0;u<8;u++)
            Q2[(g*8+u)*132 + (cp>>1)] = pack2(aq0[u], aq1[u]);
        float2 w2v = *reinterpret_cast<const float2*>(W2 + cp);
        float sq[8];
        #pragma unroll
        for (int u=0;u<8;u++) sq[u] = aq0[u]*w2v.x + aq1[u]*w2v.y;
        #pragma unroll
        for (int d=1; d<64; d<<=1){
            #pragma unroll
            for (int u=0;u<8;u++) sq[u] += __shfl_xor(sq[u], d);
        }
        if (l == 0){
            #pragma unroll
            for (int u=0;u<8;u++) SPQ[64 + (g*8+u)*2 + wp] = sq[u];
        }
    }
    __syncthreads();

    // ---- P10: value[i,j] = 0.505*(SP[i]+w*SQ[j]) + 0.495*sum_h W2[h]*|..| ----
    {
        float w00 = Wb2f[si*36 + sj], w01 = Wb2f[si*36 + sj + 16];
        float SPi = SPQ[si*2] + SPQ[si*2+1];
        float SQa = SPQ[64 + sj*2] + SPQ[64 + sj*2+1];
        float SQb = SPQ[64 + (sj+16)*2] + SPQ[64 + (sj+16)*2+1];
        float a0 = 0.f, a1 = 0.f;

        #define PROC(PA,QA,QB,H2) {                                         \
            float w2e = W2[(H2)], w2o = W2[(H2)+1];                         \
            float paE = __uint_as_float((PA)<<16), paO = __uint_as_float((PA) & 0xffff0000u); \
            float qaE = __uint_as_float((QA)<<16), qaO = __uint_as_float((QA) & 0xffff0000u); \
            float qbE = __uint_as_float((QB)<<16), qbO = __uint_as_float((QB) & 0xffff0000u); \
            float t0 = fmaf(w00, qaE, paE); a0 = fmaf(fabsf(t0), w2e, a0);  \
            float t1 = fmaf(w00, qaO, paO); a0 = fmaf(fabsf(t1), w2o, a0);  \
            float t2 = fmaf(w01, qbE, paE); a1 = fmaf(fabsf(t2), w2e, a1);  \
            float t3 = fmaf(w01, qbO, paO); a1 = fmaf(fabsf(t3), w2o, a1); }

        #pragma unroll 4
        for (int hp4 = 0; hp4 < 32; hp4++){
            uint4 pa4 = *reinterpret_cast<const uint4*>(P2 + si*128 + hp4*4);
            uint4 qa4 = *reinterpret_cast<const uint4*>(Q2 + sj*132 + hp4*4);
            uint4 qb4 = *reinterpret_cast<const uint4*>(Q2 + (sj+16)*132 + hp4*4);
            PROC(pa4.x, qa4.x, qb4.x, hp4*8+0)
            PROC(pa4.y, qa4.y, qb4.y, hp4*8+2)
            PROC(pa4.z, qa4.z, qb4.z, hp4*8+4)
            PROC(pa4.w, qa4.w, qb4.w, hp4*8+6)
        }
        #undef PROC

        float* ov = out_v + (size_t)b*1024;
        ov[si*32 + sj]      = fmaf(0.495f, a0, 0.505f*(SPi + w00*SQa));
        ov[si*32 + sj + 16] = fmaf(0.495f, a1, 0.505f*(SPi + w01*SQb));
    }
}

extern "C" void kernel_launch(void* const* d_in, const int* in_sizes, int n_in,
                              void* d_out, int out_size, void* d_ws, size_t ws_size,
                              hipStream_t stream) {
    const float* states = (const float*)d_in[0];
    const float* pol    = (const float*)d_in[1];
    const float* act    = (const float*)d_in[2];
    const float* Wkp    = (const float*)d_in[3];
    const float* Wqp    = (const float*)d_in[4];
    const float* Wvp    = (const float*)d_in[5];
    const float* Wk     = (const float*)d_in[6];
    const float* Wq     = (const float*)d_in[7];
    const float* We     = (const float*)d_in[8];
    const float* Wav    = (const float*)d_in[9];
    const float* W1     = (const float*)d_in[10];
    const float* W2     = (const float*)d_in[11];

    float* out    = (float*)d_out;
    float* out_v  = out;                 // [256,32,32,1]
    float* out_w1 = out + 256*1024;      // [256,32,32]
    float* out_w2 = out + 2*256*1024;    // [256,32,32]

    // workspace layout (floats)
    float* WABf = (float*)d_ws;                                  // [144][256] fp32 (rows 128..143 used)
    unsigned short* WABs = (unsigned short*)(WABf + 36864);      // 80 frags * 512 = 40960 ush
    unsigned short* wsu  = (unsigned short*)(WABf + 57344);
    unsigned short* Wqps = wsu;             // 32 frags * 512 = 16384 ush each
    unsigned short* Wkps = wsu + 16384;
    unsigned short* Wvps = wsu + 32768;
    unsigned short* Wqs  = wsu + 49152;
    unsigned short* Wks  = wsu + 65536;

    hipLaunchKernelGGL(k_pre, dim3(36), dim3(512), 0, stream,
                       We, Wav, W1, Wqp, Wkp, Wvp, Wq, Wk,
                       WABf, WABs, Wqps, Wkps, Wvps, Wqs, Wks);
    hipLaunchKernelGGL(k_main, dim3(NB), dim3(512), 0, stream,
                       states, pol, act,
                       Wqps, Wkps, Wvps, Wqs, Wks, WABs, WABf, W2,
                       out_v, out_w1, out_w2);
}

// Round 10
// 39.103 us; speedup vs baseline: 1.1722x; 1.1320x over previous
//
#include <hip/hip_runtime.h>
#include <math.h>

// Problem constants
#define NB 256   // batches
#define NN 32    // agents
#define DD 128   // state dim
#define NA 16    // action dim
#define HH 256   // hidden

using f32x4v  = __attribute__((ext_vector_type(4))) float;
using bf16x8  = __attribute__((ext_vector_type(8))) short;

static __device__ __forceinline__ float4 ld4(const float* p){ return *reinterpret_cast<const float4*>(p); }
static __device__ __forceinline__ void st4f(float* p, float4 v){ *reinterpret_cast<float4*>(p) = v; }
static __device__ __forceinline__ float elem(float4 v, int kk){
    return (kk==0)?v.x:(kk==1)?v.y:(kk==2)?v.z:v.w;
}

static __device__ __forceinline__ unsigned f2bf(float x){
    unsigned u = __float_as_uint(x);
    u += 0x7fffu + ((u >> 16) & 1u);   // round-to-nearest-even
    return u >> 16;
}
static __device__ __forceinline__ unsigned pack2(float a, float b){
    return f2bf(a) | (f2bf(b) << 16);
}
static __device__ __forceinline__ float bf2f(unsigned short s){
    return __uint_as_float(((unsigned)s) << 16);
}

static __device__ __forceinline__ f32x4v mfma16(bf16x8 a, bf16x8 b, f32x4v c){
    return __builtin_amdgcn_mfma_f32_16x16x32_bf16(a, b, c, 0, 0, 0);
}

static __device__ __forceinline__ bf16x8 to_bf8(const float v[8]){
    union { bf16x8 v8; unsigned u[4]; } r;
    #pragma unroll
    for (int j = 0; j < 4; j++) r.u[j] = pack2(v[2*j], v[2*j+1]);
    return r.v8;
}

// write one B-fragment (16 bf16 bytes per lane) to the swizzled weight buffer
static __device__ __forceinline__ void store_frag(unsigned short* __restrict__ dst,
                                                  int frag, int l, const float v[8]){
    uint4 p;
    p.x = pack2(v[0], v[1]); p.y = pack2(v[2], v[3]);
    p.z = pack2(v[4], v[5]); p.w = pack2(v[6], v[7]);
    *reinterpret_cast<uint4*>(dst + (size_t)(frag*64 + l)*8) = p;
}

// =============================================================================
// k_pre (36 blocks x 512) — MFMA-based:
//   blocks 0..15 : col tile ct of WAB = We @ (Wav @ W1).
//     T2-stage : T2[:,16] = Wav @ W1[:,ct*16..]  (M=128,N=16,K=128; 4 MFMA/wave;
//                A-frags direct from global Wav, B-frags direct from global W1)
//                -> T2f fp32 in LDS.
//     WAB-stage: WAB[:,16] = We_pad @ T2  (M=160,N=16,K=128; rows>=144 zero)
//                -> WABt fp32; rows 128..143 also -> WABf (fp32, for Q path).
//     Emit bf16 frags (kt 0..4, nt=ct).
//   blocks 16..35: fragment-swizzled bf16 copies of the 5 attention weights.
// Fragment layout (16x16x32 B-frag): frag (kt,nt): lane l holds
//   B[kt*32+(l>>4)*8+i][nt*16+(l&15)], i=0..7.
// =============================================================================
__global__ __launch_bounds__(512)
void k_pre(const float* __restrict__ We, const float* __restrict__ Wav,
           const float* __restrict__ W1,
           const float* __restrict__ Wqp, const float* __restrict__ Wkp,
           const float* __restrict__ Wvp, const float* __restrict__ Wq,
           const float* __restrict__ Wk,
           float* __restrict__ WABf, unsigned short* __restrict__ WABs,
           unsigned short* __restrict__ Wqps, unsigned short* __restrict__ Wkps,
           unsigned short* __restrict__ Wvps, unsigned short* __restrict__ Wqs,
           unsigned short* __restrict__ Wks)
{
    const int t = threadIdx.x;
    const int bid = blockIdx.x;

    if (bid < 16) {
        __shared__ float T2f[128*20];    // T2 col-slice fp32, pitch 20
        __shared__ float WABt[160*16];   // WAB col-tile fp32
        const int ct = bid;
        const int l  = t & 63, wvv = t >> 6;   // lane, wave
        const int lg = l >> 4;                 // k-subgroup 0..3
        const int lc = l & 15;                 // row/col within tile

        // ---- T2-stage: wave wvv owns M-tile wvv ----
        {
            const int arow = wvv*16 + lc;
            f32x4v acc = {0.f,0.f,0.f,0.f};
            #pragma unroll
            for (int kt = 0; kt < 4; kt++) {
                const float* ap = Wav + (size_t)arow*128 + kt*32 + lg*8;
                float4 a0 = ld4(ap), a1 = ld4(ap + 4);
                float av8[8] = {a0.x,a0.y,a0.z,a0.w,a1.x,a1.y,a1.z,a1.w};
                const float* bp = W1 + (size_t)(kt*32 + lg*8)*256 + ct*16 + lc;
                float bv8[8];
                #pragma unroll
                for (int i = 0; i < 8; i++) bv8[i] = bp[(size_t)i*256];
                acc = mfma16(to_bf8(av8), to_bf8(bv8), acc);
            }
            const int dr = wvv*16 + lg*4;
            #pragma unroll
            for (int r = 0; r < 4; r++) T2f[(dr+r)*20 + lc] = acc[r];
        }
        __syncthreads();

        // ---- WAB-stage: M-tiles 0..9 (wave wvv gets tile wvv; waves 0,1 also 8,9)
        #pragma unroll
        for (int pass = 0; pass < 2; pass++) {
            const int mt = (pass == 0) ? wvv : 8 + wvv;
            if (pass == 1 && wvv >= 2) continue;
            const int arow = mt*16 + lc;
            f32x4v acc = {0.f,0.f,0.f,0.f};
            #pragma unroll
            for (int kt = 0; kt < 4; kt++) {
                float av8[8];
                if (arow < 144) {
                    const float* ap = We + (size_t)arow*128 + kt*32 + lg*8;
                    float4 a0 = ld4(ap), a1 = ld4(ap + 4);
                    av8[0]=a0.x; av8[1]=a0.y; av8[2]=a0.z; av8[3]=a0.w;
                    av8[4]=a1.x; av8[5]=a1.y; av8[6]=a1.z; av8[7]=a1.w;
                } else {
                    #pragma unroll
                    for (int i = 0; i < 8; i++) av8[i] = 0.f;
                }
                float bv8[8];
                #pragma unroll
                for (int i = 0; i < 8; i++) bv8[i] = T2f[(kt*32 + lg*8 + i)*20 + lc];
                acc = mfma16(to_bf8(av8), to_bf8(bv8), acc);
            }
            const int dr = mt*16 + lg*4;
            #pragma unroll
            for (int r = 0; r < 4; r++) WABt[(dr+r)*16 + lc] = acc[r];
            if (mt == 8) {
                #pragma unroll
                for (int r = 0; r < 4; r++)
                    WABf[(size_t)(dr+r)*256 + ct*16 + lc] = acc[r];
            }
        }
        __syncthreads();

        // ---- swizzle-emit 5 frags (kt=0..4, nt=ct) ----
        if (t < 320) {
            int kt = t >> 6, ll = t & 63;
            float v[8];
            #pragma unroll
            for (int i = 0; i < 8; i++)
                v[i] = WABt[(kt*32 + (ll>>4)*8 + i)*16 + (ll&15)];
            store_frag(WABs, kt*16 + ct, ll, v);
        }
    } else {
        // 8 frags per block; 160 frags = 5 weights x 32
        const int bb = bid - 16;
        const int fg = bb*8 + (t >> 6);
        const int l  = t & 63;
        const int sel = fg >> 5, frag = fg & 31;
        const int kt = frag >> 3, nt = frag & 7;
        const float* W = (sel==0) ? Wqp : (sel==1) ? Wkp : (sel==2) ? Wvp :
                         (sel==3) ? Wq : Wk;
        unsigned short* dst = (sel==0) ? Wqps : (sel==1) ? Wkps : (sel==2) ? Wvps :
                              (sel==3) ? Wqs : Wks;
        float v[8];
        #pragma unroll
        for (int i = 0; i < 8; i++)
            v[i] = W[(kt*32 + (l>>4)*8 + i)*128 + nt*16 + (l&15)];
        store_frag(dst, frag, l, v);
    }
}

// scores+softmax, 512 threads: thread (i=t>>4, j=t&15) covers (i,j) and (i,j+16).
static __device__ __forceinline__ void scores_softmax512(const float* __restrict__ Qm,
                                                         const float* __restrict__ Km,
                                                         float scale,
                                                         float* __restrict__ w_lds,
                                                         float* __restrict__ w_out,
                                                         int i, int j)
{
    float s0 = 0.f, s1 = 0.f;
    #pragma unroll 4
    for (int k=0;k<128;k+=4){
        float4 qv = ld4(Qm + i*132 + k);
        float4 k0 = ld4(Km + j*132 + k);
        float4 k1 = ld4(Km + (j+16)*132 + k);
        s0 += qv.x*k0.x + qv.y*k0.y + qv.z*k0.z + qv.w*k0.w;
        s1 += qv.x*k1.x + qv.y*k1.y + qv.z*k1.z + qv.w*k1.w;
    }
    s0 *= scale; s1 *= scale;
    float m = fmaxf(s0, s1);
    #pragma unroll
    for (int d=1; d<16; d<<=1) m = fmaxf(m, __shfl_xor(m, d));
    float e0 = expf(s0 - m), e1 = expf(s1 - m);
    float sum = e0 + e1;
    #pragma unroll
    for (int d=1; d<16; d<<=1) sum += __shfl_xor(sum, d);
    float inv = 1.f / sum;
    e0 *= inv; e1 *= inv;
    w_lds[i*36 + j]      = e0;
    w_lds[i*36 + j + 16] = e1;
    w_out[i*32 + j]      = e0;
    w_out[i*32 + j + 16] = e1;
}

// =============================================================================
// k_main: one block per batch, 512 threads (8 waves). Identical to R9.
// =============================================================================
__global__ __launch_bounds__(512)
void k_main(const float* __restrict__ states, const float* __restrict__ pol,
            const float* __restrict__ act,
            const unsigned short* __restrict__ Wqps, const unsigned short* __restrict__ Wkps,
            const unsigned short* __restrict__ Wvps, const unsigned short* __restrict__ Wqs,
            const unsigned short* __restrict__ Wks,  const unsigned short* __restrict__ WABs,
            const float* __restrict__ WABf, const float* __restrict__ W2,
            float* __restrict__ out_v, float* __restrict__ out_w1,
            float* __restrict__ out_w2)
{
    const int b = blockIdx.x;
    const int t = threadIdx.x;
    const float scale = 0.08838834764831845f;  // 1/sqrt(128)

    __shared__ float SH[16000];   // 62.5 KB
    float* B1   = SH;                                   // 32x132
    float* B2   = SH + 4224;                            // 32x132
    float* Wb2f = SH + 8448;                            // 32x36
    float* Wb1f = SH + 9600;                            // 32x36
    float* APd  = SH + 10752;                           // 32x16 (pol-act)
    unsigned short* Xoa  = (unsigned short*)(SH + 11264); // [32][168] bf16 (st|act|0)
    unsigned short* Ubf  = (unsigned short*)B1;           // [32][136] bf16
    unsigned short* Wvbf = (unsigned short*)B2;           // [32][136] bf16
    float*    A1 = SH;                                   // [32][260] fp32 (over B1+B2)
    unsigned* P2 = (unsigned*)(SH + 11904);              // [32][128] packed bf16 (over dead Xoa)
    unsigned* Q2 = (unsigned*)SH;                        // [32][132] packed bf16 (over dead A1)
    float* SPQ = Wb1f;   // SP[32][2] at 0, SQ[32][2] at +64 (Wb1f dead after P3)

    const float* stg  = states + (size_t)b*(NN*DD);
    const float* actg = act + (size_t)b*(NN*NA);
    const float* polg = pol + (size_t)b*(NN*NA);

    // ---- stage Xoa = bf16([st | act | 0]) (k 0..159), APd = pol-act ----
    {
        int r = t >> 4, kb = t & 15;
        #pragma unroll
        for (int uu = 0; uu < 10; uu++){
            int k = kb + 16*uu;
            float v = (k < 128) ? stg[r*128 + k]
                    : (k < 144) ? actg[r*16 + (k-128)] : 0.f;
            Xoa[r*168 + k] = (unsigned short)f2bf(v);
        }
        if (t < 128) {
            int rr = t>>2, cc = (t&3)*4;
            float4 p = ld4(polg + rr*16 + cc), a = ld4(actg + rr*16 + cc);
            st4f(APd + rr*16 + cc, make_float4(p.x-a.x, p.y-a.y, p.z-a.z, p.w-a.w));
        }
    }
    __syncthreads();

    // MFMA wave geometry
    const int l    = t & 63;
    const int wv   = t >> 6;             // wave 0..7
    const int mt   = wv & 1;             // M-tile
    const int ntb  = (wv >> 1) * 2;      // N-tile base (128-col GEMMs)
    const int nb7  = (wv >> 1) * 4;      // N-tile base (256-col GEMM)
    const int arow = mt*16 + (l & 15);
    const int drow = mt*16 + ((l >> 4) << 2);
    const int dcol = l & 15;

    // VALU phase geometry
    const int c  = t & 127;
    const int g  = t >> 7;
    const int cp = (t & 127)*2;
    const int si = t >> 4;
    const int sj = t & 15;
    const int wp = wv & 1;

    // ---- P1 (MFMA dual): q1 = st@Wqp -> B1, k1 = st@Wkp -> B2 ----
    {
        f32x4v aq0={0.f,0.f,0.f,0.f}, aq1={0.f,0.f,0.f,0.f};
        f32x4v ak0={0.f,0.f,0.f,0.f}, ak1={0.f,0.f,0.f,0.f};
        const unsigned short* ab = Xoa + arow*168 + (l>>4)*8;
        #pragma unroll
        for (int kt = 0; kt < 4; kt++){
            bf16x8 a   = *reinterpret_cast<const bf16x8*>(ab + kt*32);
            bf16x8 bq0 = *reinterpret_cast<const bf16x8*>(Wqps + (size_t)((kt*8+ntb  )*64 + l)*8);
            bf16x8 bq1 = *reinterpret_cast<const bf16x8*>(Wqps + (size_t)((kt*8+ntb+1)*64 + l)*8);
            bf16x8 bk0 = *reinterpret_cast<const bf16x8*>(Wkps + (size_t)((kt*8+ntb  )*64 + l)*8);
            bf16x8 bk1 = *reinterpret_cast<const bf16x8*>(Wkps + (size_t)((kt*8+ntb+1)*64 + l)*8);
            aq0 = mfma16(a, bq0, aq0); aq1 = mfma16(a, bq1, aq1);
            ak0 = mfma16(a, bk0, ak0); ak1 = mfma16(a, bk1, ak1);
        }
        #pragma unroll
        for (int r = 0; r < 4; r++){
            B1[(drow+r)*132 + ntb*16     + dcol] = aq0[r];
            B1[(drow+r)*132 + (ntb+1)*16 + dcol] = aq1[r];
            B2[(drow+r)*132 + ntb*16     + dcol] = ak0[r];
            B2[(drow+r)*132 + (ntb+1)*16 + dcol] = ak1[r];
        }
    }
    __syncthreads();

    // ---- P2: w1 = softmax(q1@k1^T * scale) ----
    scores_softmax512(B1, B2, scale, Wb1f, out_w1 + (size_t)b*1024, si, sj);
    __syncthreads();

    // ---- P3 (VALU): u = w1@st -> Ubf (bf16, over B1) ----
    {
        float au[8];
        #pragma unroll
        for (int u=0;u<8;u++) au[u]=0.f;
        #pragma unroll
        for (int k0=0;k0<32;k0+=4){
            float4 xv[8];
            #pragma unroll
            for (int u=0;u<8;u++) xv[u] = ld4(Wb1f + (g*8+u)*36 + k0);
            #pragma unroll
            for (int kk=0;kk<4;kk++){
                float w = bf2f(Xoa[(k0+kk)*168 + c]);
                #pragma unroll
                for (int u=0;u<8;u++) au[u] = fmaf(elem(xv[u],kk), w, au[u]);
            }
        }
        __syncthreads();   // B1/scores traffic done before bf16 overwrite
        #pragma unroll
        for (int u=0;u<8;u++) Ubf[(g*8+u)*136 + c] = (unsigned short)f2bf(au[u]);
    }
    __syncthreads();

    // ---- P4 (MFMA): wav1 = u@Wvp -> Wvbf (bf16, over B2) ----
    {
        f32x4v av0={0.f,0.f,0.f,0.f}, av1={0.f,0.f,0.f,0.f};
        const unsigned short* ab = Ubf + arow*136 + (l>>4)*8;
        #pragma unroll
        for (int kt = 0; kt < 4; kt++){
            bf16x8 a  = *reinterpret_cast<const bf16x8*>(ab + kt*32);
            bf16x8 b0 = *reinterpret_cast<const bf16x8*>(Wvps + (size_t)((kt*8+ntb  )*64 + l)*8);
            bf16x8 b1 = *reinterpret_cast<const bf16x8*>(Wvps + (size_t)((kt*8+ntb+1)*64 + l)*8);
            av0 = mfma16(a, b0, av0); av1 = mfma16(a, b1, av1);
        }
        #pragma unroll
        for (int r = 0; r < 4; r++){
            Wvbf[(drow+r)*136 + ntb*16     + dcol] = (unsigned short)f2bf(av0[r]);
            Wvbf[(drow+r)*136 + (ntb+1)*16 + dcol] = (unsigned short)f2bf(av1[r]);
        }
    }
    __syncthreads();

    // ---- P5 (MFMA dual): q2 = wav1@Wq, k2 = wav1@Wk -> regs -> B1,B2 ----
    {
        f32x4v aq0={0.f,0.f,0.f,0.f}, aq1={0.f,0.f,0.f,0.f};
        f32x4v ak0={0.f,0.f,0.f,0.f}, ak1={0.f,0.f,0.f,0.f};
        const unsigned short* ab = Wvbf + arow*136 + (l>>4)*8;
        #pragma unroll
        for (int kt = 0; kt < 4; kt++){
            bf16x8 a   = *reinterpret_cast<const bf16x8*>(ab + kt*32);
            bf16x8 bq0 = *reinterpret_cast<const bf16x8*>(Wqs + (size_t)((kt*8+ntb  )*64 + l)*8);
            bf16x8 bq1 = *reinterpret_cast<const bf16x8*>(Wqs + (size_t)((kt*8+ntb+1)*64 + l)*8);
            bf16x8 bk0 = *reinterpret_cast<const bf16x8*>(Wks + (size_t)((kt*8+ntb  )*64 + l)*8);
            bf16x8 bk1 = *reinterpret_cast<const bf16x8*>(Wks + (size_t)((kt*8+ntb+1)*64 + l)*8);
            aq0 = mfma16(a, bq0, aq0); aq1 = mfma16(a, bq1, aq1);
            ak0 = mfma16(a, bk0, ak0); ak1 = mfma16(a, bk1, ak1);
        }
        __syncthreads();   // everyone done reading Wvbf
        #pragma unroll
        for (int r = 0; r < 4; r++){
            B1[(drow+r)*132 + ntb*16     + dcol] = aq0[r];
            B1[(drow+r)*132 + (ntb+1)*16 + dcol] = aq1[r];
            B2[(drow+r)*132 + ntb*16     + dcol] = ak0[r];
            B2[(drow+r)*132 + (ntb+1)*16 + dcol] = ak1[r];
        }
    }
    __syncthreads();

    // ---- P6: w2 = softmax(q2@k2^T * scale) ----
    scores_softmax512(B1, B2, scale, Wb2f, out_w2 + (size_t)b*1024, si, sj);
    __syncthreads();

    // ---- P7 (MFMA): A1 = [st|act|0]@WAB (K=160, N=256) -> A1 (over B1/B2) ----
    {
        f32x4v ac[4];
        #pragma unroll
        for (int n=0;n<4;n++) ac[n] = f32x4v{0.f,0.f,0.f,0.f};
        const unsigned short* ab = Xoa + arow*168 + (l>>4)*8;
        #pragma unroll
        for (int kt = 0; kt < 5; kt++){
            bf16x8 a = *reinterpret_cast<const bf16x8*>(ab + kt*32);
            #pragma unroll
            for (int n = 0; n < 4; n++){
                bf16x8 bb = *reinterpret_cast<const bf16x8*>(WABs + (size_t)((kt*16 + nb7 + n)*64 + l)*8);
                ac[n] = mfma16(a, bb, ac[n]);
            }
        }
        #pragma unroll
        for (int n = 0; n < 4; n++){
            #pragma unroll
            for (int r = 0; r < 4; r++)
                A1[(drow+r)*260 + (nb7+n)*16 + dcol] = ac[n][r];
        }
    }
    __syncthreads();

    // ---- P8 (VALU): P = w2@A1 (K=32) -> bf16 P2 (over dead Xoa) + SP ----
    {
        float ap0[8], ap1[8];
        #pragma unroll
        for (int u=0;u<8;u++){ ap0[u]=0.f; ap1[u]=0.f; }
        #pragma unroll
        for (int k0=0;k0<32;k0+=4){
            float4 xv[8];
            #pragma unroll
            for (int u=0;u<8;u++) xv[u] = ld4(Wb2f + (g*8+u)*36 + k0);
            #pragma unroll
            for (int kk=0;kk<4;kk++){
                float2 w = *reinterpret_cast<const float2*>(A1 + (k0+kk)*260 + cp);
                #pragma unroll
                for (int u=0;u<8;u++){
                    float x = elem(xv[u],kk);
                    ap0[u] = fmaf(x, w.x, ap0[u]);
                    ap1[u] = fmaf(x, w.y, ap1[u]);
                }
            }
        }
        __syncthreads();  // A1/Xoa reads done before P2 overwrite
        #pragma unroll
        for (int u=0;u<8;u++)
            P2[(g*8+u)*128 + (cp>>1)] = pack2(ap0[u], ap1[u]);
        // SP[row] = sum_h W2[h]*P[row][h]: per-lane partial + wave butterfly
        float2 w2v = *reinterpret_cast<const float2*>(W2 + cp);
        float sp[8];
        #pragma unroll
        for (int u=0;u<8;u++) sp[u] = ap0[u]*w2v.x + ap1[u]*w2v.y;
        #pragma unroll
        for (int d=1; d<64; d<<=1){
            #pragma unroll
            for (int u=0;u<8;u++) sp[u] += __shfl_xor(sp[u], d);
        }
        if (l == 0){
            #pragma unroll
            for (int u=0;u<8;u++) SPQ[(g*8+u)*2 + wp] = sp[u];
        }
    }
    __syncthreads();

    // ---- P9 (VALU): Q = (pol-act)@WB (K=16) -> bf16 Q2 (over dead A1) + SQ ----
    {
        float aq0[8], aq1[8];
        #pragma unroll
        for (int u=0;u<8;u++){ aq0[u]=0.f; aq1[u]=0.f; }
        const float* wB = WABf + 128*256;
        #pragma unroll
        for (int k0=0;k0<16;k0+=4){
            float4 xv[8];
            #pragma unroll
            for (int u=0;u<8;u++) xv[u] = ld4(APd + (g*8+u)*16 + k0);
            #pragma unroll
            for (int kk=0;kk<4;kk++){
                float2 w = *reinterpret_cast<const float2*>(wB + (k0+kk)*256 + cp);
                #pragma unroll
                for (int u=0;u<8;u++){
                    float x = elem(xv[u],kk);
                    aq0[u] = fmaf(x, w.x, aq0[u]);
                    aq1[u] = fmaf(x, w.y, aq1[u]);
                }
            }
        }
        #pragma unroll
        for (int u=0;u<8;u++)
            Q2[(g*8+u)*132 + (cp>>1)] = pack2(aq0[u], aq1[u]);
        float2 w2v = *reinterpret_cast<const float2*>(W2 + cp);
        float sq[8];
        #pragma unroll
        for (int u=0;u<8;u++) sq[u] = aq0[u]*w2v.x + aq1[u]*w2v.y;
        #pragma unroll
        for (int d=1; d<64; d<<=1){
            #pragma unroll
            for (int u=0;u<8;u++) sq[u] += __shfl_xor(sq[u], d);
        }
        if (l == 0){
            #pragma unroll
            for (int u=0;u<8;u++) SPQ[64 + (g*8+u)*2 + wp] = sq[u];
        }
    }
    __syncthreads();

    // ---- P10: value[i,j] = 0.505*(SP[i]+w*SQ[j]) + 0.495*sum_h W2[h]*|..| ----
    {
        float w00 = Wb2f[si*36 + sj], w01 = Wb2f[si*36 + sj + 16];
        float SPi = SPQ[si*2] + SPQ[si*2+1];
        float SQa = SPQ[64 + sj*2] + SPQ[64 + sj*2+1];
        float SQb = SPQ[64 + (sj+16)*2] + SPQ[64 + (sj+16)*2+1];
        float a0 = 0.f, a1 = 0.f;

        #define PROC(PA,QA,QB,H2) {                                         \
            float w2e = W2[(H2)], w2o = W2[(H2)+1];                         \
            float paE = __uint_as_float((PA)<<16), paO = __uint_as_float((PA) & 0xffff0000u); \
            float qaE = __uint_as_float((QA)<<16), qaO = __uint_as_float((QA) & 0xffff0000u); \
            float qbE = __uint_as_float((QB)<<16), qbO = __uint_as_float((QB) & 0xffff0000u); \
            float t0 = fmaf(w00, qaE, paE); a0 = fmaf(fabsf(t0), w2e, a0);  \
            float t1 = fmaf(w00, qaO, paO); a0 = fmaf(fabsf(t1), w2o, a0);  \
            float t2 = fmaf(w01, qbE, paE); a1 = fmaf(fabsf(t2), w2e, a1);  \
            float t3 = fmaf(w01, qbO, paO); a1 = fmaf(fabsf(t3), w2o, a1); }

        #pragma unroll 4
        for (int hp4 = 0; hp4 < 32; hp4++){
            uint4 pa4 = *reinterpret_cast<const uint4*>(P2 + si*128 + hp4*4);
            uint4 qa4 = *reinterpret_cast<const uint4*>(Q2 + sj*132 + hp4*4);
            uint4 qb4 = *reinterpret_cast<const uint4*>(Q2 + (sj+16)*132 + hp4*4);
            PROC(pa4.x, qa4.x, qb4.x, hp4*8+0)
            PROC(pa4.y, qa4.y, qb4.y, hp4*8+2)
            PROC(pa4.z, qa4.z, qb4.z, hp4*8+4)
            PROC(pa4.w, qa4.w, qb4.w, hp4*8+6)
        }
        #undef PROC

        float* ov = out_v + (size_t)b*1024;
        ov[si*32 + sj]      = fmaf(0.495f, a0, 0.505f*(SPi + w00*SQa));
        ov[si*32 + sj + 16] = fmaf(0.495f, a1, 0.505f*(SPi + w01*SQb));
    }
}

extern "C" void kernel_launch(void* const* d_in, const int* in_sizes, int n_in,
                              void* d_out, int out_size, void* d_ws, size_t ws_size,
                              hipStream_t stream) {
    const float* states = (const float*)d_in[0];
    const float* pol    = (const float*)d_in[1];
    const float* act    = (const float*)d_in[2];
    const float* Wkp    = (const float*)d_in[3];
    const float* Wqp    = (const float*)d_in[4];
    const float* Wvp    = (const float*)d_in[5];
    const float* Wk     = (const float*)d_in[6];
    const float* Wq     = (const float*)d_in[7];
    const float* We     = (const float*)d_in[8];
    const float* Wav    = (const float*)d_in[9];
    const float* W1     = (const float*)d_in[10];
    const float* W2     = (const float*)d_in[11];

    float* out    = (float*)d_out;
    float* out_v  = out;                 // [256,32,32,1]
    float* out_w1 = out + 256*1024;      // [256,32,32]
    float* out_w2 = out + 2*256*1024;    // [256,32,32]

    // workspace layout (floats)
    float* WABf = (float*)d_ws;                                  // [144][256] fp32 (rows 128..143 used)
    unsigned short* WABs = (unsigned short*)(WABf + 36864);      // 80 frags * 512 = 40960 ush
    unsigned short* wsu  = (unsigned short*)(WABf + 57344);
    unsigned short* Wqps = wsu;             // 32 frags * 512 = 16384 ush each
    unsigned short* Wkps = wsu + 16384;
    unsigned short* Wvps = wsu + 32768;
    unsigned short* Wqs  = wsu + 49152;
    unsigned short* Wks  = wsu + 65536;

    hipLaunchKernelGGL(k_pre, dim3(36), dim3(512), 0, stream,
                       We, Wav, W1, Wqp, Wkp, Wvp, Wq, Wk,
                       WABf, WABs, Wqps, Wkps, Wvps, Wqs, Wks);
    hipLaunchKernelGGL(k_main, dim3(NB), dim3(512), 0, stream,
                       states, pol, act,
                       Wqps, Wkps, Wvps, Wqs, Wks, WABs, WABf, W2,
                       out_v, out_w1, out_w2);
}